// Round 3
// baseline (215.873 us; speedup 1.0000x reference)
//
#include <hip/hip_runtime.h>

// Problem constants (from reference setup_inputs)
#define BB   64          // batch
#define SS   512         // seq len
#define HH   768         // hidden dim
#define WW   256         // MAX_WORD_LEN (words per batch)
#define WE   300         // word-embedding dim
#define OUTD (HH + WE)   // 1068 output feature dim
#define WPB  8           // words per block
#define CPB  (WW / WPB)  // 32 word-chunks per batch
#define H4   (HH / 4)    // 192 float4s per hidden row
#define O4   (OUTD / 4)  // 267 float4s per out row
#define W4   (WE / 4)    // 75 float4s per w2v row

// ---------------------------------------------------------------------------
// Kernel A: bounds[b*(WW+1)+w] = lower_bound(token_ids[b,:], w); bounds[b][WW]=SS
// ---------------------------------------------------------------------------
__global__ __launch_bounds__(256)
void seg_bounds_kernel(const int* __restrict__ token_ids,  // [B, S]
                       int* __restrict__ bounds)           // [B, WW+1]
{
    const int b = blockIdx.x;
    const int w = threadIdx.x;
    const int* tk = token_ids + b * SS;
    int l = 0, r = SS;
    while (l < r) { int m = (l + r) >> 1; if (tk[m] < w) l = m + 1; else r = m; }
    bounds[b * (WW + 1) + w] = l;
    if (w == 0) bounds[b * (WW + 1) + WW] = SS;
}

// ---------------------------------------------------------------------------
// Kernel B: one block per (b, 8-word chunk). Waves 0-2 stream the contiguous
// hidden rows [bnd[w0], bnd[w0+8]) in chunks of 4 (4 loads in flight/wave),
// flushing per-word means at wave-uniform boundaries (bounds broadcast from
// registers via __shfl — zero memory traffic in the loop). Wave 3 gathers the
// 8 w2v rows, 2 words per unrolled iteration.
// ---------------------------------------------------------------------------
__global__ __launch_bounds__(256, 8)
void EmbeddingsModule_45311904973549_kernel(
    const float* __restrict__ hidden,     // [B, S, H]
    const float* __restrict__ w2v,        // [VOCAB, WE]
    const int*   __restrict__ bounds,     // [B, WW+1]
    const int*   __restrict__ word_ids,   // [B, W]
    float*       __restrict__ out)        // [B, W, OUTD]
{
    const int blk  = blockIdx.x;          // 0 .. BB*CPB-1
    const int b    = blk / CPB;
    const int w0   = (blk % CPB) * WPB;
    const int tid  = threadIdx.x;
    const int lane = tid & 63;

    if (tid < 192) {
        // --- load the 9 boundary values into lanes 0..8, broadcast via shfl ---
        const int* bp   = bounds + b * (WW + 1) + w0;
        int        bval = (lane <= WPB) ? bp[lane] : 0;
        int s    = __shfl(bval, 0);
        int end  = __shfl(bval, WPB);
        int w    = 0;
        int segstart = s;
        int hi   = __shfl(bval, 1);
        float4 acc = make_float4(0.f, 0.f, 0.f, 0.f);

        const float4* hp    = (const float4*)hidden + (size_t)b * SS * H4 + tid;
        float4*       obase = (float4*)out + (size_t)(b * WW + w0) * O4 + tid;

        // flush every word whose segment ends at or before snow (wave-uniform)
        auto flushUpTo = [&](int snow) {
            while (w < WPB && snow >= hi) {
                int   c   = hi - segstart;
                float inv = (c > 0) ? (1.0f / (float)c) : 0.0f;
                obase[(size_t)w * O4] =
                    make_float4(acc.x * inv, acc.y * inv, acc.z * inv, acc.w * inv);
                acc = make_float4(0.f, 0.f, 0.f, 0.f);
                segstart = hi;
                ++w;
                if (w < WPB) hi = __shfl(bval, w + 1);
            }
        };

        // --- stream rows in chunks of 4 (independent loads, deep MLP) ---
        while (s + 4 <= end) {
            float4 v0 = hp[(size_t)(s + 0) * H4];
            float4 v1 = hp[(size_t)(s + 1) * H4];
            float4 v2 = hp[(size_t)(s + 2) * H4];
            float4 v3 = hp[(size_t)(s + 3) * H4];
            flushUpTo(s);
            acc.x += v0.x; acc.y += v0.y; acc.z += v0.z; acc.w += v0.w;
            flushUpTo(s + 1);
            acc.x += v1.x; acc.y += v1.y; acc.z += v1.z; acc.w += v1.w;
            flushUpTo(s + 2);
            acc.x += v2.x; acc.y += v2.y; acc.z += v2.z; acc.w += v2.w;
            flushUpTo(s + 3);
            acc.x += v3.x; acc.y += v3.y; acc.z += v3.z; acc.w += v3.w;
            s += 4;
        }
        while (s < end) {
            float4 v = hp[(size_t)s * H4];
            flushUpTo(s);
            acc.x += v.x; acc.y += v.y; acc.z += v.z; acc.w += v.w;
            ++s;
        }
        flushUpTo(0x7fffffff);   // flush remaining words (incl. trailing empties)
    } else {
        // --- w2v gather: 8 rows, 2 per iteration, fully unrolled ---
        int widv = (lane < WPB) ? word_ids[b * WW + w0 + lane] : 0;
        #pragma unroll
        for (int w = 0; w < WPB; w += 2) {
            const int wid0 = __shfl(widv, w);
            const int wid1 = __shfl(widv, w + 1);
            const float4* r0 = (const float4*)(w2v + (size_t)wid0 * WE);
            const float4* r1 = (const float4*)(w2v + (size_t)wid1 * WE);
            float4* o0 = (float4*)(out + (size_t)(b * WW + w0 + w    ) * OUTD + HH);
            float4* o1 = (float4*)(out + (size_t)(b * WW + w0 + w + 1) * OUTD + HH);
            float4 a0 = r0[lane];
            float4 a1 = r1[lane];
            const bool e = lane < (W4 - 64);   // 11 tail float4s
            float4 b0, b1;
            if (e) { b0 = r0[64 + lane]; b1 = r1[64 + lane]; }
            o0[lane] = a0;
            o1[lane] = a1;
            if (e) { o0[64 + lane] = b0; o1[64 + lane] = b1; }
        }
    }
}

extern "C" void kernel_launch(void* const* d_in, const int* in_sizes, int n_in,
                              void* d_out, int out_size, void* d_ws, size_t ws_size,
                              hipStream_t stream) {
    const float* hidden    = (const float*)d_in[0];
    const float* w2v       = (const float*)d_in[1];
    const int*   token_ids = (const int*)d_in[2];
    const int*   word_ids  = (const int*)d_in[3];
    float*       out       = (float*)d_out;
    int*         bounds    = (int*)d_ws;   // B*(WW+1) ints = 65.8 KB

    seg_bounds_kernel<<<BB, 256, 0, stream>>>(token_ids, bounds);
    EmbeddingsModule_45311904973549_kernel<<<BB * CPB, 256, 0, stream>>>(
        hidden, w2v, bounds, word_ids, out);
}